// Round 11
// baseline (414.530 us; speedup 1.0000x reference)
//
#include <hip/hip_runtime.h>
#include <cstdint>
#include <cstddef>

#define LRELU(x) fmaxf((x), 0.2f*(x))

typedef float v2f __attribute__((ext_vector_type(2)));
typedef __attribute__((ext_vector_type(8))) short short8;
typedef __attribute__((ext_vector_type(4))) float f32x4;

__device__ inline unsigned short f2bf(float f) {
  unsigned u = __float_as_uint(f);
  u += 0x8000u;
  return (unsigned short)(u >> 16);
}

// ------- GEMM1 (MFMA bf16): h1f8[N,128](fp8) = x @ W1, fused a_s1/a_d1 -------
__global__ __launch_bounds__(256) void k_gemm1(const float* __restrict__ x,
                                               const float* __restrict__ W1,
                                               const float* __restrict__ atts1,
                                               const float* __restrict__ attd1,
                                               int* __restrict__ h1f8,
                                               float* __restrict__ a_s, float* __restrict__ a_d,
                                               int* __restrict__ deg_s, int M8,
                                               float* __restrict__ poolcnt,
                                               int N) {
  __shared__ short Wt[128*136];   // 34816 B; reused as f32 hs (4x16x132) after MFMA
  int t = threadIdx.x;
  int gid = blockIdx.x*256 + t;
  for (int z = gid; z < M8; z += gridDim.x*256) deg_s[z] = 0;
  if (gid < 1408) poolcnt[gid] = 0.f;

  // stage Wt[n][k] = bf16(W1[k][n])
  {
    int n = t & 127, half = t >> 7;
    for (int kk0 = 0; kk0 < 64; kk0 += 4) {
      short v0 = (short)f2bf(W1[(half*64 + kk0 + 0)*128 + n]);
      short v1 = (short)f2bf(W1[(half*64 + kk0 + 1)*128 + n]);
      short v2 = (short)f2bf(W1[(half*64 + kk0 + 2)*128 + n]);
      short v3 = (short)f2bf(W1[(half*64 + kk0 + 3)*128 + n]);
      *(short4*)(&Wt[n*136 + half*64 + kk0]) = make_short4(v0, v1, v2, v3);
    }
  }
  __syncthreads();

  int w = t >> 6, l = t & 63;
  int n0 = blockIdx.x*64 + w*16;
  int mrow = l & 15, q = l >> 4;
  int nrow = n0 + mrow; if (nrow >= N) nrow = N - 1;
  const float4* xrow = (const float4*)(x + (size_t)nrow*128);
  f32x4 acc[8];
  #pragma unroll
  for (int i = 0; i < 8; ++i) acc[i] = (f32x4){0.f, 0.f, 0.f, 0.f};
  #pragma unroll
  for (int kc = 0; kc < 4; ++kc) {
    float4 xa = xrow[kc*8 + q*2];
    float4 xb = xrow[kc*8 + q*2 + 1];
    short8 afr;
    afr[0] = (short)f2bf(xa.x); afr[1] = (short)f2bf(xa.y);
    afr[2] = (short)f2bf(xa.z); afr[3] = (short)f2bf(xa.w);
    afr[4] = (short)f2bf(xb.x); afr[5] = (short)f2bf(xb.y);
    afr[6] = (short)f2bf(xb.z); afr[7] = (short)f2bf(xb.w);
    #pragma unroll
    for (int ti = 0; ti < 8; ++ti) {
      short8 bfr = *(const short8*)(&Wt[(ti*16 + mrow)*136 + kc*32 + q*8]);
      acc[ti] = __builtin_amdgcn_mfma_f32_16x16x32_bf16(afr, bfr, acc[ti], 0, 0, 0);
    }
  }
  __syncthreads();   // all waves done reading Wt; reuse as hs
  float* hs = ((float*)Wt) + w*2112;   // 16 rows x 132 per wave
  #pragma unroll
  for (int ti = 0; ti < 8; ++ti) {
    #pragma unroll
    for (int r = 0; r < 4; ++r)
      hs[(q*4 + r)*132 + ti*16 + mrow] = acc[ti][r];
  }
  {
    int nd = l >> 2, head = l & 3;
    int ndg = n0 + nd;
    const float4* hr  = (const float4*)(hs + nd*132 + head*32);
    const float4* asv = (const float4*)(atts1 + head*32);
    const float4* adv = (const float4*)(attd1 + head*32);
    float ps = 0.f, pd = 0.f;
    int pk[8];
    #pragma unroll
    for (int j = 0; j < 8; ++j) {
      float4 v = hr[j];
      float4 sa = asv[j], da = adv[j];
      ps += v.x*sa.x + v.y*sa.y + v.z*sa.z + v.w*sa.w;
      pd += v.x*da.x + v.y*da.y + v.z*da.z + v.w*da.w;
      int p = __builtin_amdgcn_cvt_pk_fp8_f32(v.x, v.y, 0, false);
      p = __builtin_amdgcn_cvt_pk_fp8_f32(v.z, v.w, p, true);
      pk[j] = p;
    }
    if (ndg < N) {
      int4* dst = (int4*)(h1f8 + (size_t)ndg*32 + head*8);
      dst[0] = make_int4(pk[0], pk[1], pk[2], pk[3]);
      dst[1] = make_int4(pk[4], pk[5], pk[6], pk[7]);
      a_s[ndg*4 + head] = ps;
      a_d[ndg*4 + head] = pd;
    }
  }
}

// -------- CSR build, XCD-sharded --------
__global__ __launch_bounds__(256) void k_hist_sh(const int* __restrict__ ei, int E, int Etot,
                                                 int N, int* __restrict__ deg_s) {
  int e = blockIdx.x*256 + threadIdx.x;
  if (e >= Etot) return;
  int s = blockIdx.x & 7;
  int dst = (e < E) ? ei[E + e] : (e - E);
  atomicAdd(&deg_s[s*N + dst], 1);
}

__global__ __launch_bounds__(1024) void k_scan1v(const int* __restrict__ vin,
    int* __restrict__ vout, int* __restrict__ bsums, int M) {
  __shared__ int wsum[16];
  int t = threadIdx.x;
  int lane = t & 63, wave = t >> 6;
  size_t base = (size_t)blockIdx.x*4096 + (size_t)t*4;
  int4 v = make_int4(0,0,0,0);
  if (base + 3 < (size_t)M) {
    v = *(const int4*)(vin + base);
  } else {
    if (base+0 < (size_t)M) v.x = vin[base+0];
    if (base+1 < (size_t)M) v.y = vin[base+1];
    if (base+2 < (size_t)M) v.z = vin[base+2];
    if (base+3 < (size_t)M) v.w = vin[base+3];
  }
  int s0 = v.x, s1 = s0 + v.y, s2 = s1 + v.z, tot = s2 + v.w;
  int inc = tot;
  #pragma unroll
  for (int off = 1; off < 64; off <<= 1) {
    int u = __shfl_up(inc, off, 64);
    if (lane >= off) inc += u;
  }
  if (lane == 63) wsum[wave] = inc;
  __syncthreads();
  if (t < 16) {
    int w = wsum[t];
    int iw = w;
    #pragma unroll
    for (int off = 1; off < 16; off <<= 1) {
      int u = __shfl_up(iw, off, 16);
      if (t >= off) iw += u;
    }
    wsum[t] = iw - w;
    if (t == 15) bsums[blockIdx.x] = iw;
  }
  __syncthreads();
  int offb = wsum[wave] + (inc - tot);
  int4 o = make_int4(offb, offb + s0, offb + s1, offb + s2);
  if (base + 3 < (size_t)M) {
    *(int4*)(vout + base) = o;
  } else {
    if (base+0 < (size_t)M) vout[base+0] = o.x;
    if (base+1 < (size_t)M) vout[base+1] = o.y;
    if (base+2 < (size_t)M) vout[base+2] = o.z;
    if (base+3 < (size_t)M) vout[base+3] = o.w;
  }
}

__global__ __launch_bounds__(256) void k_scan3A(int* __restrict__ SP,
    int* __restrict__ cursor, const int* __restrict__ bsums, int nb, int M, int total) {
  __shared__ int sc[256];
  int t = threadIdx.x;
  sc[t] = (t < nb) ? bsums[t] : 0;
  __syncthreads();
  for (int off = 1; off < 256; off <<= 1) {
    int v = (t >= off) ? sc[t - off] : 0;
    __syncthreads();
    sc[t] += v;
    __syncthreads();
  }
  int i = blockIdx.x*256 + t;
  if (i < M) {
    int blk = i >> 12;
    int add = (blk == 0) ? 0 : sc[blk - 1];
    int r = SP[i] + add;
    SP[i] = r;
    cursor[i] = r;
  }
  if (i == 0) SP[M] = total;
}

__global__ __launch_bounds__(256) void k_scatter_sh(const int* __restrict__ ei, int E, int Etot,
    int N, int* __restrict__ cursor, int* __restrict__ srcs_sh) {
  int e = blockIdx.x*256 + threadIdx.x;
  if (e >= Etot) return;
  int s = blockIdx.x & 7;
  int src, dst;
  if (e < E) { src = ei[e]; dst = ei[E + e]; } else { src = e - E; dst = src; }
  int pos = atomicAdd(&cursor[s*N + dst], 1);
  srcs_sh[pos] = src;
}

// compact: pure shard-major -> dst-major copy + rowptr (8 lanes per dst)
__global__ __launch_bounds__(256) void k_compact(const int* __restrict__ SP,
    const int* __restrict__ srcs_sh, int* __restrict__ srcs,
    int* __restrict__ rowptr, int N, int Etot) {
  int tid = blockIdx.x*256 + threadIdx.x;
  if (tid == 0) rowptr[N] = Etot;
  int dst = tid >> 3;
  if (dst >= N) return;
  int s = tid & 7;
  int shbase = SP[s*N];
  int bg = SP[s*N + dst];
  int cnt = SP[s*N + dst + 1] - bg;
  int t_s = bg - shbase;
  int rsum = t_s;
  rsum += __shfl_xor(rsum, 1, 8);
  rsum += __shfl_xor(rsum, 2, 8);
  rsum += __shfl_xor(rsum, 4, 8);
  int incl = cnt;
  #pragma unroll
  for (int d = 1; d < 8; d <<= 1) {
    int o = __shfl_up(incl, d, 8);
    if (s >= d) incl += o;
  }
  int base = rsum + (incl - cnt);
  if (s == 0) rowptr[dst] = rsum;
  for (int k = 0; k < cnt; ++k) srcs[base + k] = srcs_sh[bg + k];
}

// -------- layer-1 aggregation (fp8 gather, lane-split exp) + fused GEMM2 --------
// g output now packed fp8: gb row = int4 (10 bytes used) per dst.
__global__ __launch_bounds__(256) void k_agg1g2(const int* __restrict__ rowptr,
    const int* __restrict__ srcs, const float* __restrict__ a_s,
    const float* __restrict__ a_d, const int* __restrict__ h1f8,
    const float* __restrict__ b1, const float* __restrict__ W2,
    const float* __restrict__ atts2, const float* __restrict__ attd2,
    int4* __restrict__ gb, float* __restrict__ a_s2, float* __restrict__ a_d2,
    int N) {
  __shared__ float W2t[1280];   // W2t[c*128 + k] = W2[k*10 + c]
  __shared__ float att2s[20];
  int t = threadIdx.x;
  for (int f = t; f < 1280; f += 256) {
    int c = f >> 7, k = f & 127;
    W2t[f] = W2[k*10 + c];
  }
  if (t < 20) att2s[t] = (t < 10) ? atts2[t] : attd2[t - 10];
  __syncthreads();

  int dst = (blockIdx.x*256 + t) >> 5;
  if (dst >= N) return;
  int l = t & 31;
  int head = l >> 3;
  int eh = l & 3;
  int ee = l >> 2;
  int beg = rowptr[dst], end = rowptr[dst+1];
  float4 ad4 = ((const float4*)a_d)[dst];
  float adh = (eh==0) ? ad4.x : (eh==1) ? ad4.y : (eh==2) ? ad4.z : ad4.w;
  float denom = 0.f;
  float4 acc = make_float4(0.f, 0.f, 0.f, 0.f);
  for (int j = beg; j < end; j += 8) {
    int rm = end - j - 1;
    int je = j + (ee < rm ? ee : rm);
    int se = srcs[je];
    float4 as4 = ((const float4*)a_s)[se];
    float ash = (eh==0) ? as4.x : (eh==1) ? as4.y : (eh==2) ? as4.z : as4.w;
    float w = __expf(LRELU(ash + adh));
    if (ee > rm) w = 0.f;
    #pragma unroll
    for (int e = 0; e < 8; ++e) {
      int s_e   = __shfl(se, e*4, 32);
      float w_e = __shfl(w, e*4 + head, 32);
      int u = h1f8[(size_t)s_e*32 + l];
      v2f lo = __builtin_amdgcn_cvt_pk_f32_fp8(u, false);
      v2f hi = __builtin_amdgcn_cvt_pk_f32_fp8(u, true);
      acc.x += w_e*lo.x; acc.y += w_e*lo.y;
      acc.z += w_e*hi.x; acc.w += w_e*hi.y;
      denom += w_e;
    }
  }
  float inv = 1.0f / (denom + 1e-16f);
  float4 b14 = ((const float4*)b1)[l];
  float h0 = acc.x*inv + b14.x; h0 = h0 > 0.f ? h0 : __expf(h0) - 1.0f;
  float h1v = acc.y*inv + b14.y; h1v = h1v > 0.f ? h1v : __expf(h1v) - 1.0f;
  float h2v = acc.z*inv + b14.z; h2v = h2v > 0.f ? h2v : __expf(h2v) - 1.0f;
  float h3v = acc.w*inv + b14.w; h3v = h3v > 0.f ? h3v : __expf(h3v) - 1.0f;
  const float4* W2t4 = (const float4*)W2t;
  float p[10];
  #pragma unroll
  for (int c = 0; c < 10; ++c) {
    float4 wv = W2t4[c*32 + l];
    p[c] = h0*wv.x + h1v*wv.y + h2v*wv.z + h3v*wv.w;
  }
  #pragma unroll
  for (int off = 16; off > 0; off >>= 1) {
    #pragma unroll
    for (int c = 0; c < 10; ++c)
      p[c] += __shfl_xor(p[c], off, 32);
  }
  if (l == 0) {
    int g0 = __builtin_amdgcn_cvt_pk_fp8_f32(p[0], p[1], 0, false);
    g0 = __builtin_amdgcn_cvt_pk_fp8_f32(p[2], p[3], g0, true);
    int g1 = __builtin_amdgcn_cvt_pk_fp8_f32(p[4], p[5], 0, false);
    g1 = __builtin_amdgcn_cvt_pk_fp8_f32(p[6], p[7], g1, true);
    int g2 = __builtin_amdgcn_cvt_pk_fp8_f32(p[8], p[9], 0, false);
    gb[dst] = make_int4(g0, g1, g2, 0);
    float as = 0.f, adv = 0.f;
    #pragma unroll
    for (int c = 0; c < 10; ++c) {
      as  += p[c]*att2s[c];
      adv += p[c]*att2s[10 + c];
    }
    a_s2[dst] = as;
    a_d2[dst] = adv;
  }
}

// -------- layer-2 aggregation: LANE-PER-DST, fp8 g (L2-resident), fused pool --------
__global__ __launch_bounds__(256) void k_agg2f(const int* __restrict__ rowptr,
    const int* __restrict__ srcs, const float* __restrict__ a_s,
    const float* __restrict__ a_d, const int4* __restrict__ gb,
    const float* __restrict__ b2, const int* __restrict__ batch,
    float* __restrict__ pooled, float* __restrict__ cnt, int N) {
  int t = threadIdx.x;
  int dst = blockIdx.x*256 + t;
  bool valid = (dst < N);
  int dc = valid ? dst : N - 1;
  int beg = rowptr[dc], end = rowptr[dc+1];
  float ad = a_d[dc];
  float acc[10] = {};
  float denom = 0.f;
  for (int j = beg; j < end; ++j) {
    int s = srcs[j];
    float w = __expf(LRELU(a_s[s] + ad));
    int4 G = gb[s];
    v2f p01 = __builtin_amdgcn_cvt_pk_f32_fp8(G.x, false);
    v2f p23 = __builtin_amdgcn_cvt_pk_f32_fp8(G.x, true);
    v2f p45 = __builtin_amdgcn_cvt_pk_f32_fp8(G.y, false);
    v2f p67 = __builtin_amdgcn_cvt_pk_f32_fp8(G.y, true);
    v2f p89 = __builtin_amdgcn_cvt_pk_f32_fp8(G.z, false);
    denom += w;
    acc[0] += w*p01.x; acc[1] += w*p01.y;
    acc[2] += w*p23.x; acc[3] += w*p23.y;
    acc[4] += w*p45.x; acc[5] += w*p45.y;
    acc[6] += w*p67.x; acc[7] += w*p67.y;
    acc[8] += w*p89.x; acc[9] += w*p89.y;
  }
  float inv = 1.0f / (denom + 1e-16f);
  float o[10];
  #pragma unroll
  for (int c = 0; c < 10; ++c) {
    float v = acc[c]*inv + b2[c];
    o[c] = v > 0.f ? v : __expf(v) - 1.0f;
  }
  int b = batch[dc];
  int bfirst = __builtin_amdgcn_readfirstlane(b);
  bool fast = __all(valid && (b == bfirst));
  if (fast) {
    #pragma unroll
    for (int off = 32; off > 0; off >>= 1) {
      #pragma unroll
      for (int c = 0; c < 10; ++c) o[c] += __shfl_xor(o[c], off, 64);
    }
    if ((t & 63) == 0) {
      #pragma unroll
      for (int c = 0; c < 10; ++c) atomicAdd(&pooled[bfirst*10 + c], o[c]);
      atomicAdd(&cnt[bfirst], 64.0f);
    }
  } else if (valid) {
    #pragma unroll
    for (int c = 0; c < 10; ++c) atomicAdd(&pooled[b*10 + c], o[c]);
    atomicAdd(&cnt[b], 1.0f);
  }
}

__global__ __launch_bounds__(128) void k_softmax(const float* __restrict__ pooled,
    const float* __restrict__ cnt, float* __restrict__ out) {
  int t = threadIdx.x;
  float inv = 1.0f / fmaxf(cnt[t], 1.0f);
  float v[10], m = -1e30f;
  #pragma unroll
  for (int c = 0; c < 10; ++c) { v[c] = pooled[t*10 + c] * inv; m = fmaxf(m, v[c]); }
  float s = 0.f;
  #pragma unroll
  for (int c = 0; c < 10; ++c) s += __expf(v[c] - m);
  float ls = logf(s) + m;
  #pragma unroll
  for (int c = 0; c < 10; ++c) out[t*10 + c] = v[c] - ls;
}

extern "C" void kernel_launch(void* const* d_in, const int* in_sizes, int n_in,
                              void* d_out, int out_size, void* d_ws, size_t ws_size,
                              hipStream_t stream) {
  const float* x     = (const float*)d_in[0];
  const float* W1    = (const float*)d_in[1];
  const float* atts1 = (const float*)d_in[2];
  const float* attd1 = (const float*)d_in[3];
  const float* b1    = (const float*)d_in[4];
  const float* W2    = (const float*)d_in[5];
  const float* atts2 = (const float*)d_in[6];
  const float* attd2 = (const float*)d_in[7];
  const float* b2    = (const float*)d_in[8];
  const int*   ei    = (const int*)d_in[9];
  const int*   batch = (const int*)d_in[10];
  int N = in_sizes[10];
  int E = in_sizes[9] / 2;
  int Etot = E + N;
  int M8 = 8 * N;

  char* base = (char*)d_ws;
  size_t off = 0;
  auto allocB = [&](size_t bytes) { void* p = (void*)(base + off); off += (bytes + 63) & ~size_t(63); return p; };

  int*   h1f8   = (int*)allocB((size_t)N*32*sizeof(int));
  float* a_s1   = (float*)allocB((size_t)N*4*sizeof(float));
  float* a_d1   = (float*)allocB((size_t)N*4*sizeof(float));
  int4*  gb     = (int4*)allocB((size_t)N*sizeof(int4));
  float* a_s2   = (float*)allocB((size_t)N*sizeof(float));
  float* a_d2   = (float*)allocB((size_t)N*sizeof(float));
  float* poolcnt= (float*)allocB(1408*sizeof(float));   // pooled[1280] + cnt[128]
  int* deg_s  = (int*)allocB((size_t)M8*sizeof(int));
  int* SP     = (int*)allocB((size_t)(M8+1)*sizeof(int));
  int* cursor = (int*)allocB((size_t)M8*sizeof(int));
  int* rowptr = (int*)allocB((size_t)(N+1)*sizeof(int));
  int* bsumsA = (int*)allocB(1024*sizeof(int));
  int* srcs_sh= (int*)allocB((size_t)(Etot+16)*sizeof(int));
  int* srcs   = (int*)allocB((size_t)(Etot+16)*sizeof(int));

  float* pooled = poolcnt;
  float* cnt    = poolcnt + 1280;
  int nbA = (M8 + 4095) / 4096;

  k_gemm1<<<dim3((N + 63)/64), dim3(256), 0, stream>>>(x, W1, atts1, attd1, h1f8,
                                                       a_s1, a_d1, deg_s, M8, poolcnt, N);
  k_hist_sh<<<dim3((Etot + 255)/256), dim3(256), 0, stream>>>(ei, E, Etot, N, deg_s);
  k_scan1v<<<dim3(nbA), dim3(1024), 0, stream>>>(deg_s, SP, bsumsA, M8);
  k_scan3A<<<dim3((M8 + 255)/256), dim3(256), 0, stream>>>(SP, cursor, bsumsA, nbA, M8, Etot);
  k_scatter_sh<<<dim3((Etot + 255)/256), dim3(256), 0, stream>>>(ei, E, Etot, N, cursor, srcs_sh);
  k_compact<<<dim3((N*8 + 255)/256), dim3(256), 0, stream>>>(SP, srcs_sh, srcs, rowptr, N, Etot);
  k_agg1g2<<<dim3((N*32 + 255)/256), dim3(256), 0, stream>>>(rowptr, srcs, a_s1, a_d1, h1f8,
                                                             b1, W2, atts2, attd2,
                                                             gb, a_s2, a_d2, N);
  k_agg2f<<<dim3((N + 255)/256), dim3(256), 0, stream>>>(rowptr, srcs, a_s2, a_d2, gb,
                                                         b2, batch, pooled, cnt, N);
  k_softmax<<<dim3(1), dim3(128), 0, stream>>>(pooled, cnt, (float*)d_out);
}